// Round 2
// baseline (428.466 us; speedup 1.0000x reference)
//
#include <hip/hip_runtime.h>

// Problem constants (from reference setup_inputs):
//   B=16, T=4096 routing slots, D=512 embed dim, max_nodes=1024, max_edges=2048
#define NB 16
#define NT 4096
#define ND 512
#define ND4 128           // D / 4 floats per float4
#define MAX_NODES 1024
#define MAX_EDGES 2048
#define NODE_ROWS 2048    // max_nodes * 2 (repeat 2)
#define EDGE_ROWS 10240   // max_edges * 5 (repeat 5)

// ---------------------------------------------------------------------------
// Kernel 1: stable stream compaction via packed prefix scan.
// One block per batch row. 1024 threads x 4 elements (int4 load).
// packed counter: high 16 bits = #zeros, low 16 bits = #ones (max 4096 each,
// no cross-field carry possible).
// ---------------------------------------------------------------------------
__global__ __launch_bounds__(1024) void compact_kernel(
    const int* __restrict__ routing,
    int* __restrict__ node_pos,   // [NB][MAX_NODES]
    int* __restrict__ edge_pos)   // [NB][MAX_EDGES]
{
    const int b   = blockIdx.x;
    const int tid = threadIdx.x;           // 0..1023
    const int lane = tid & 63;
    const int wv   = tid >> 6;             // wave id, 0..15

    const int4 v = reinterpret_cast<const int4*>(routing + b * NT)[tid];
    const int e0 = v.x, e1 = v.y, e2 = v.z, e3 = v.w;

    // within-thread inclusive packed prefix over the 4 elements
    unsigned inc0 = ((e0 == 0) ? 0x10000u : 0u) | ((e0 == 1) ? 1u : 0u);
    unsigned inc1 = ((e1 == 0) ? 0x10000u : 0u) | ((e1 == 1) ? 1u : 0u);
    unsigned inc2 = ((e2 == 0) ? 0x10000u : 0u) | ((e2 == 1) ? 1u : 0u);
    unsigned inc3 = ((e3 == 0) ? 0x10000u : 0u) | ((e3 == 1) ? 1u : 0u);
    unsigned p0 = inc0;
    unsigned p1 = p0 + inc1;
    unsigned p2 = p1 + inc2;
    unsigned p3 = p2 + inc3;
    const unsigned my_sum = p3;

    // wave-64 inclusive scan of per-thread sums
    unsigned x = my_sum;
    #pragma unroll
    for (int off = 1; off < 64; off <<= 1) {
        unsigned y = __shfl_up(x, off, 64);
        if (lane >= off) x += y;
    }

    __shared__ unsigned wave_sums[16];
    if (lane == 63) wave_sums[wv] = x;

    // init the output slots to -1 while the scan data settles
    node_pos[b * MAX_NODES + tid] = -1;
    edge_pos[b * MAX_EDGES + 2 * tid + 0] = -1;
    edge_pos[b * MAX_EDGES + 2 * tid + 1] = -1;
    __syncthreads();

    unsigned offset = 0;
    for (int i = 0; i < wv; ++i) offset += wave_sums[i];

    // exclusive packed prefix at this thread's first element
    const unsigned base = offset + x - my_sum;

    const unsigned ex0 = base;
    const unsigned ex1 = base + p0;
    const unsigned ex2 = base + p1;
    const unsigned ex3 = base + p2;

    const int t0 = tid * 4;
    #pragma unroll 4
    for (int i = 0; i < 4; ++i) {
        const int      e  = (i == 0) ? e0 : (i == 1) ? e1 : (i == 2) ? e2 : e3;
        const unsigned ex = (i == 0) ? ex0 : (i == 1) ? ex1 : (i == 2) ? ex2 : ex3;
        if (e == 0) {
            const unsigned rank = ex >> 16;
            if (rank < MAX_NODES) node_pos[b * MAX_NODES + rank] = t0 + i;
        } else if (e == 1) {
            const unsigned rank = ex & 0xFFFFu;
            if (rank < MAX_EDGES) edge_pos[b * MAX_EDGES + rank] = t0 + i;
        }
    }
}

// ---------------------------------------------------------------------------
// Kernel 2a: node_pe gather. One float4 per thread, 128 threads per out row.
// out row r (0..NB*NODE_ROWS-1): b = r/2048, j = r%2048, tok = node_pos[b][j>>1]
// ---------------------------------------------------------------------------
__global__ __launch_bounds__(256) void gather_node_kernel(
    const float4* __restrict__ pe,        // [4096][ND4]
    const int* __restrict__ node_pos,     // [NB][MAX_NODES]
    float4* __restrict__ out)             // [NB*NODE_ROWS][ND4]
{
    const unsigned gid = blockIdx.x * 256u + threadIdx.x;   // < NB*NODE_ROWS*128
    const unsigned row = gid >> 7;
    const unsigned c   = gid & 127u;
    const unsigned b   = row >> 11;        // /2048
    const unsigned j   = row & 2047u;
    const int tok = node_pos[b * MAX_NODES + (j >> 1)];
    const int src = tok < 0 ? 0 : tok;
    out[(size_t)row * ND4 + c] = pe[(size_t)src * ND4 + c];
}

// ---------------------------------------------------------------------------
// Kernel 2b: edge_pe gather.
// out row r (0..NB*EDGE_ROWS-1): b = r/10240, j = r%10240, tok = edge_pos[b][j/5]
// ---------------------------------------------------------------------------
__global__ __launch_bounds__(256) void gather_edge_kernel(
    const float4* __restrict__ pe,
    const int* __restrict__ edge_pos,     // [NB][MAX_EDGES]
    float4* __restrict__ out)             // [NB*EDGE_ROWS][ND4]
{
    const unsigned gid = blockIdx.x * 256u + threadIdx.x;   // < NB*EDGE_ROWS*128
    const unsigned row = gid >> 7;
    const unsigned c   = gid & 127u;
    const unsigned b   = row / EDGE_ROWS;  // magic-mul division
    const unsigned j   = row - b * EDGE_ROWS;
    const int tok = edge_pos[b * MAX_EDGES + j / 5u];
    const int src = tok < 0 ? 0 : tok;
    out[(size_t)row * ND4 + c] = pe[(size_t)src * ND4 + c];
}

extern "C" void kernel_launch(void* const* d_in, const int* in_sizes, int n_in,
                              void* d_out, int out_size, void* d_ws, size_t ws_size,
                              hipStream_t stream) {
    // inputs (setup_inputs order): routing [16,4096] i32, max_nodes (1024),
    // max_edges (2048), pos_embed [4096,512] f32
    const int*   routing = (const int*)d_in[0];
    const float* pe      = (const float*)d_in[3];

    int* node_pos = (int*)d_ws;                          // 16*1024 ints = 64 KB
    int* edge_pos = node_pos + NB * MAX_NODES;           // 16*2048 ints = 128 KB

    float* out_node = (float*)d_out;                                  // [16,2048,512]
    float* out_edge = out_node + (size_t)NB * NODE_ROWS * ND;         // [16,10240,512]

    compact_kernel<<<NB, 1024, 0, stream>>>(routing, node_pos, edge_pos);

    const unsigned node_threads = NB * NODE_ROWS * ND4;   // 4,194,304
    const unsigned edge_threads = NB * EDGE_ROWS * ND4;   // 20,971,520
    gather_node_kernel<<<node_threads / 256, 256, 0, stream>>>(
        (const float4*)pe, node_pos, (float4*)out_node);
    gather_edge_kernel<<<edge_threads / 256, 256, 0, stream>>>(
        (const float4*)pe, edge_pos, (float4*)out_edge);
}

// Round 3
// 404.205 us; speedup vs baseline: 1.0600x; 1.0600x over previous
//
#include <hip/hip_runtime.h>

// Problem constants (from reference setup_inputs):
//   B=16, T=4096 routing slots, D=512 embed dim, max_nodes=1024, max_edges=2048
#define NB 16
#define NT 4096
#define ND 512
#define ND4 128           // D / 4 floats per float4
#define MAX_NODES 1024
#define MAX_EDGES 2048
#define NODE_ROWS 2048    // max_nodes * 2 (repeat 2)
#define EDGE_ROWS 10240   // max_edges * 5 (repeat 5)
#define ROWS_NODE_TOT 32768u   // NB * NODE_ROWS
#define ROWS_TOTAL 196608u     // NB * (NODE_ROWS + EDGE_ROWS)

typedef __attribute__((ext_vector_type(4))) float f4;

// ---------------------------------------------------------------------------
// Kernel 1: stable stream compaction via packed prefix scan.
// One block per batch row. 1024 threads x 4 elements (int4 load).
// packed counter: high 16 bits = #zeros, low 16 bits = #ones (max 4096 each,
// no cross-field carry possible).
// ---------------------------------------------------------------------------
__global__ __launch_bounds__(1024) void compact_kernel(
    const int* __restrict__ routing,
    int* __restrict__ node_pos,   // [NB][MAX_NODES]
    int* __restrict__ edge_pos)   // [NB][MAX_EDGES]
{
    const int b   = blockIdx.x;
    const int tid = threadIdx.x;           // 0..1023
    const int lane = tid & 63;
    const int wv   = tid >> 6;             // wave id, 0..15

    const int4 v = reinterpret_cast<const int4*>(routing + b * NT)[tid];
    const int e0 = v.x, e1 = v.y, e2 = v.z, e3 = v.w;

    // within-thread inclusive packed prefix over the 4 elements
    unsigned inc0 = ((e0 == 0) ? 0x10000u : 0u) | ((e0 == 1) ? 1u : 0u);
    unsigned inc1 = ((e1 == 0) ? 0x10000u : 0u) | ((e1 == 1) ? 1u : 0u);
    unsigned inc2 = ((e2 == 0) ? 0x10000u : 0u) | ((e2 == 1) ? 1u : 0u);
    unsigned inc3 = ((e3 == 0) ? 0x10000u : 0u) | ((e3 == 1) ? 1u : 0u);
    unsigned p0 = inc0;
    unsigned p1 = p0 + inc1;
    unsigned p2 = p1 + inc2;
    unsigned p3 = p2 + inc3;
    const unsigned my_sum = p3;

    // wave-64 inclusive scan of per-thread sums
    unsigned x = my_sum;
    #pragma unroll
    for (int off = 1; off < 64; off <<= 1) {
        unsigned y = __shfl_up(x, off, 64);
        if (lane >= off) x += y;
    }

    __shared__ unsigned wave_sums[16];
    if (lane == 63) wave_sums[wv] = x;

    // init the output slots to -1 while the scan data settles
    node_pos[b * MAX_NODES + tid] = -1;
    edge_pos[b * MAX_EDGES + 2 * tid + 0] = -1;
    edge_pos[b * MAX_EDGES + 2 * tid + 1] = -1;
    __syncthreads();

    unsigned offset = 0;
    for (int i = 0; i < wv; ++i) offset += wave_sums[i];

    // exclusive packed prefix at this thread's first element
    const unsigned base = offset + x - my_sum;

    const unsigned ex0 = base;
    const unsigned ex1 = base + p0;
    const unsigned ex2 = base + p1;
    const unsigned ex3 = base + p2;

    const int t0 = tid * 4;
    #pragma unroll 4
    for (int i = 0; i < 4; ++i) {
        const int      e  = (i == 0) ? e0 : (i == 1) ? e1 : (i == 2) ? e2 : e3;
        const unsigned ex = (i == 0) ? ex0 : (i == 1) ? ex1 : (i == 2) ? ex2 : ex3;
        if (e == 0) {
            const unsigned rank = ex >> 16;
            if (rank < MAX_NODES) node_pos[b * MAX_NODES + rank] = t0 + i;
        } else if (e == 1) {
            const unsigned rank = ex & 0xFFFFu;
            if (rank < MAX_EDGES) edge_pos[b * MAX_EDGES + rank] = t0 + i;
        }
    }
}

// ---------------------------------------------------------------------------
// Kernel 2: fused gather for both outputs. 64 threads per output row; each
// thread moves 2 float4s (two dense 1 KB bursts per wave = one 2 KB pe row).
// Output rows: [0, 32768) = node_pe region, [32768, 196608) = edge_pe region
// (the two tuple outputs are contiguous in d_out).
// Stores are non-temporal: output is write-once, never re-read — keep it out
// of L2 so pos_embed (8 MB) stays cache-resident for the gather reads.
// ---------------------------------------------------------------------------
__global__ __launch_bounds__(256) void gather_fused_kernel(
    const float4* __restrict__ pe,        // [4096][ND4]
    const int* __restrict__ node_pos,     // [NB][MAX_NODES]
    const int* __restrict__ edge_pos,     // [NB][MAX_EDGES]
    float4* __restrict__ out)             // [ROWS_TOTAL][ND4]
{
    const unsigned gid = blockIdx.x * 256u + threadIdx.x;
    const unsigned row = gid >> 6;         // 0..ROWS_TOTAL-1
    const unsigned t   = gid & 63u;

    int tok;
    if (row < ROWS_NODE_TOT) {
        const unsigned b = row >> 11;          // /NODE_ROWS
        const unsigned j = row & 2047u;
        tok = node_pos[b * MAX_NODES + (j >> 1)];
    } else {
        const unsigned r2 = row - ROWS_NODE_TOT;
        const unsigned b  = r2 / EDGE_ROWS;    // magic-mul division
        const unsigned j  = r2 - b * EDGE_ROWS;
        tok = edge_pos[b * MAX_EDGES + j / 5u];
    }
    const int src = tok < 0 ? 0 : tok;

    const f4* srcp = (const f4*)(pe + (size_t)src * ND4);
    f4* dstp       = (f4*)(out + (size_t)row * ND4);

    const f4 v0 = srcp[t];
    const f4 v1 = srcp[t + 64];
    __builtin_nontemporal_store(v0, dstp + t);
    __builtin_nontemporal_store(v1, dstp + t + 64);
}

extern "C" void kernel_launch(void* const* d_in, const int* in_sizes, int n_in,
                              void* d_out, int out_size, void* d_ws, size_t ws_size,
                              hipStream_t stream) {
    // inputs (setup_inputs order): routing [16,4096] i32, max_nodes (1024),
    // max_edges (2048), pos_embed [4096,512] f32
    const int*   routing = (const int*)d_in[0];
    const float* pe      = (const float*)d_in[3];

    int* node_pos = (int*)d_ws;                          // 16*1024 ints = 64 KB
    int* edge_pos = node_pos + NB * MAX_NODES;           // 16*2048 ints = 128 KB

    compact_kernel<<<NB, 1024, 0, stream>>>(routing, node_pos, edge_pos);

    const unsigned total_threads = ROWS_TOTAL * 64u;     // 12,582,912
    gather_fused_kernel<<<total_threads / 256, 256, 0, stream>>>(
        (const float4*)pe, node_pos, edge_pos, (float4*)d_out);
}